// Round 10
// baseline (280.692 us; speedup 1.0000x reference)
//
#include <hip/hip_runtime.h>

// Span masking — bit-exact JAX threefry2x32 stream (verified R5/R6/R9), batched.
// R10: serial key chain on VALU with v_alignbit_b32 rotates. Round = add->xor
// (rotate of OLD v1 hides in the add's shadow) => ~2 dep levels/round vs 3-4
// for any 2-instr rotate; dependent-op latency ~4cyc (m07) sets the cost.
// R9 SALU chain measured ~620 cyc/link; this targets ~200.
// Chain runs redundantly on all 64 lanes (lockstep); lane t captures
// key_{base+t} via cndmask (off critical path). No barriers during the walk
// (single wave: DS ops execute in issue order). 256-thread block: waves 1-3
// sleep at one barrier, then 4x-parallel epilogue (epilogue is latency-bound).
//
// Stream (jax_threefry_partitionable=True):
//   split(key,n): keys[i] = (y0,y1) of tf(key,(0,i))
//   random_bits(key,32,(128,))[r] = y0^y1 of tf(key,(0,r))
//   _randint: (k1,k2)=split(key,2); span=2^13 -> start = bits(k2)[r] & 8191
//   _uniform: bits(key) directly

static constexpr int kB = 128;
static constexpr int kS = 8192;
static constexpr int kWords = kS / 32;   // 256
static constexpr int kMaskTok = 50256;
static constexpr int kBatch = 64;
static constexpr int kMaxBatches = 96;

__device__ __forceinline__ unsigned rotl32(unsigned x, int r) {
#if __has_builtin(__builtin_amdgcn_alignbit)
  // v_alignbit_b32 dst,s0,s1,s2 = ((s0:s1) >> s2)[31:0]; s0==s1==x -> rotr.
  return __builtin_amdgcn_alignbit(x, x, (unsigned)(32 - r));
#else
  return (x << r) | (x >> (32 - r));
#endif
}

// Full threefry2x32-20 with explicit counter (phase-2 draws, per-lane keys).
__device__ __forceinline__ void tf2x32(unsigned k0, unsigned k1,
                                       unsigned x0, unsigned x1,
                                       unsigned& y0, unsigned& y1) {
  const unsigned ks0 = k0, ks1 = k1, ks2 = k0 ^ k1 ^ 0x1BD11BDAu;
  unsigned v0 = x0 + ks0;
  unsigned v1 = x1 + ks1;
#define TF_R(r) do { v0 += v1; v1 = rotl32(v1, r); v1 ^= v0; } while (0)
  TF_R(13); TF_R(15); TF_R(26); TF_R(6);
  v0 += ks1; v1 += ks2 + 1u;
  TF_R(17); TF_R(29); TF_R(16); TF_R(24);
  v0 += ks2; v1 += ks0 + 2u;
  TF_R(13); TF_R(15); TF_R(26); TF_R(6);
  v0 += ks0; v1 += ks1 + 3u;
  TF_R(17); TF_R(29); TF_R(16); TF_R(24);
  v0 += ks1; v1 += ks2 + 4u;
  TF_R(13); TF_R(15); TF_R(26); TF_R(6);
  v0 += ks2; v1 += ks0 + 5u;
  y0 = v0; y1 = v1;
}

// Chain link: (k0,k1) <- tf(k0,k1, x=(0,0)) — counter zero folds the first
// injection into the init (v0=k0, v1=k1).
__device__ __forceinline__ void tf_link(unsigned& k0, unsigned& k1) {
  const unsigned ks0 = k0, ks1 = k1, ks2 = k0 ^ k1 ^ 0x1BD11BDAu;
  unsigned v0 = k0, v1 = k1;
  TF_R(13); TF_R(15); TF_R(26); TF_R(6);
  v0 += ks1; v1 += ks2 + 1u;
  TF_R(17); TF_R(29); TF_R(16); TF_R(24);
  v0 += ks2; v1 += ks0 + 2u;
  TF_R(13); TF_R(15); TF_R(26); TF_R(6);
  v0 += ks0; v1 += ks1 + 3u;
  TF_R(17); TF_R(29); TF_R(16); TF_R(24);
  v0 += ks1; v1 += ks2 + 4u;
  TF_R(13); TF_R(15); TF_R(26); TF_R(6);
  v0 += ks2; v1 += ks0 + 5u;
#undef TF_R
  k0 = v0; k1 = v1;
}

__global__ __launch_bounds__(256)
void span_mask_kernel(const int* __restrict__ x0tok,
                      const float* __restrict__ mask_prob,
                      int* __restrict__ out) {
  const int r = blockIdx.x;
  const int tid = threadIdx.x;

  __shared__ __align__(16) unsigned maskw[kWords];
  for (int i = tid; i < kWords; i += 256) maskw[i] = 0u;
  __syncthreads();

  if (tid < 64) {  // wave 0 does the whole RNG walk; no barriers inside
    const int lane = tid;
    const int target = (int)floorf(mask_prob[r] * 8192.0f);  // *2^13 exact
    const float Cf = -0.40546512603759765625f;  // f32(log1p(-f32(1/3)))

    unsigned key0 = 0u, key1 = 42u;  // jax.random.key(42)
    int cur = 0;

    for (int b = 0; b < kMaxBatches; ++b) {
      // ---- phase 1: 64 chain links, all lanes lockstep; lane t captures ---
      unsigned mk0 = 0u, mk1 = 0u;
#pragma unroll 4
      for (int t = 0; t < kBatch; ++t) {
        const bool sel = (lane == t);
        mk0 = sel ? key0 : mk0;     // v_cmp+cndmask, off the chain's path
        mk1 = sel ? key1 : mk1;
        tf_link(key0, key1);        // key <- subkey 0 of split(key,3)
      }

      // ---- phase 2: per-lane draws for iteration b*64+lane ----------------
      unsigned ksA, ksB, klA, klB, k2A, k2B, d0, d1, e0, e1;
      tf2x32(mk0, mk1, 0u, 1u, ksA, ksB);        // ks = subkey 1
      tf2x32(mk0, mk1, 0u, 2u, klA, klB);        // kl = subkey 2
      tf2x32(ksA, ksB, 0u, 1u, k2A, k2B);        // k2 = split(ks,2)[1]
      tf2x32(k2A, k2B, 0u, (unsigned)r, d0, d1); // start bits
      tf2x32(klA, klB, 0u, (unsigned)r, e0, e1); // uniform bits
      const int start = (int)((d0 ^ d1) & 8191u);
      const unsigned ubits = e0 ^ e1;

      float f = __uint_as_float((ubits >> 9) | 0x3F800000u) - 1.0f;  // exact
      float val = __fadd_rn(__fmul_rn(f, (1.0f - 1e-7f)), 1e-7f);    // no FMA
      float u = fmaxf(1e-7f, val);
      float lf = (float)log((double)u);   // correctly-rounded f32 log
      float q = __fdiv_rn(lf, Cf);
      int geo = (int)floorf(q) + 1;       // 1..40
      int len = min(geo, kS - start);
      const int end = start + len;

      // ---- phase 3: optimistic apply; exact count from atomic returns -----
      // Single wave: DS ops execute in issue order; no barriers needed.
      uint4 pre = *(const uint4*)&maskw[4 * lane];  // pre-batch snapshot
      const int w0 = start >> 5, w1 = (end - 1) >> 5;  // <=3 words (len<=40)
      int d = 0;
#pragma unroll
      for (int k = 0; k < 3; ++k) {
        int w = w0 + k;
        if (w <= w1) {
          int lo = max(start - (w << 5), 0);
          int hi = min(end - (w << 5), 32);
          unsigned bits = (hi >= 32 ? 0xFFFFFFFFu : ((1u << hi) - 1u))
                          & (0xFFFFFFFFu << lo);
          unsigned old = atomicOr(&maskw[w], bits);
          d += __popc(bits & ~old);  // Σ over ops = |new union bits| exact
        }
      }
#pragma unroll
      for (int off = 1; off < 64; off <<= 1) d += __shfl_xor(d, off);
      const int newcur = cur + d;

      if (newcur < target) { cur = newcur; continue; }  // batch fully valid

      // ---- crossing batch: restore pre-state, exact serial replay ---------
      *(uint4*)&maskw[4 * lane] = pre;
#pragma unroll 1
      for (int i = 0; i < kBatch; ++i) {
        if (cur >= target) break;
        int st = __shfl(start, i);
        int en = __shfl(end, i);
        int iw0 = st >> 5, iw1 = (en - 1) >> 5;
        int dd = 0;
        int w = iw0 + lane;
        if (w <= iw1) {
          int lo = max(st - (w << 5), 0);
          int hi = min(en - (w << 5), 32);
          unsigned bits = (hi >= 32 ? 0xFFFFFFFFu : ((1u << hi) - 1u))
                          & (0xFFFFFFFFu << lo);
          unsigned old = maskw[w];
          maskw[w] = old | bits;
          dd = __popc(bits & ~old);
        }
        dd += __shfl_xor(dd, 1);
        dd += __shfl_xor(dd, 2);
        cur += __shfl(dd, 0);
      }
      break;  // row done
    }
  }

  __syncthreads();  // waves 1-3 waited here during the walk

  // ---- epilogue: 4-wave int4-vectorized writes of x_masked and mask -------
  const int base4 = r * (kS / 4);
  for (int i = tid; i < kS / 4; i += 256) {
    int4 tok = ((const int4*)x0tok)[base4 + i];
    unsigned nib = maskw[i >> 3] >> ((i & 7) * 4);
    int4 xm, mm;
    mm.x = (int)(nib & 1u);        xm.x = mm.x ? kMaskTok : tok.x;
    mm.y = (int)((nib >> 1) & 1u); xm.y = mm.y ? kMaskTok : tok.y;
    mm.z = (int)((nib >> 2) & 1u); xm.z = mm.z ? kMaskTok : tok.z;
    mm.w = (int)((nib >> 3) & 1u); xm.w = mm.w ? kMaskTok : tok.w;
    ((int4*)out)[base4 + i] = xm;
    ((int4*)out)[kB * (kS / 4) + base4 + i] = mm;
  }
}

extern "C" void kernel_launch(void* const* d_in, const int* in_sizes, int n_in,
                              void* d_out, int out_size, void* d_ws, size_t ws_size,
                              hipStream_t stream) {
  const int* x0 = (const int*)d_in[0];
  const float* mp = (const float*)d_in[1];
  int* out = (int*)d_out;
  hipLaunchKernelGGL(span_mask_kernel, dim3(kB), dim3(256), 0, stream,
                     x0, mp, out);
}

// Round 11
// 177.684 us; speedup vs baseline: 1.5797x; 1.5797x over previous
//
#include <hip/hip_runtime.h>

// Span masking — bit-exact JAX threefry2x32 stream (verified R5/R6/R9), batched.
// R11: chain link as PURE-VALU inline asm. Round = v_add (v0+=v1) -> v_xor,
// with v_alignbit (1-instr rotate of OLD v1) off the critical path => ~2 dep
// levels/round; injections fused via v_add3_u32. ~47 levels x 4 cyc ~= 200
// cyc/link vs 620 (R9 SALU) / 780 (R10 mixed). Captures are v->v cndmask
// (no s<->v hazards). Rows already run concurrently (128 blocks); wall time
// == one row's chain latency, so per-link latency is the only lever.
//
// Stream (jax_threefry_partitionable=True):
//   split(key,n): keys[i] = (y0,y1) of tf(key,(0,i))
//   random_bits(key,32,(128,))[r] = y0^y1 of tf(key,(0,r))
//   _randint: (k1,k2)=split(key,2); span=2^13 -> start = bits(k2)[r] & 8191
//   _uniform: bits(key) directly

static constexpr int kB = 128;
static constexpr int kS = 8192;
static constexpr int kWords = kS / 32;   // 256
static constexpr int kMaskTok = 50256;
static constexpr int kBatch = 64;
static constexpr int kMaxBatches = 96;

// One round on (v0,v1), rotate amount r, rr = 32-r (alignbit is a rotr by rr).
#define TF_VRND(rr) \
  "v_add_u32 %[v0], %[v0], %[v1]\n\t" \
  "v_alignbit_b32 %[t], %[v1], %[v1], " #rr "\n\t" \
  "v_xor_b32 %[v1], %[t], %[v0]\n\t"

// (k0,k1) <- tf2x32(k0,k1, x=(0,0)), pure VALU.
// Round groups {13,15,26,6}/{17,29,16,24}x2 + {13,15,26,6}; rr=32-r:
// 13->19, 15->17, 26->6, 6->26, 17->15, 29->3, 16->16, 24->8.
__device__ __forceinline__ void tf_link_valu(unsigned& k0, unsigned& k1) {
  unsigned v0, v1, t, ks2;
  asm("v_xor_b32 %[ks2], %[k0], %[k1]\n\t"
      "v_xor_b32 %[ks2], 0x1BD11BDA, %[ks2]\n\t"      // literal in src0
      // group 1 (13,15,26,6) — first round reads k0,k1 directly (x=0 init)
      "v_add_u32 %[v0], %[k0], %[k1]\n\t"
      "v_alignbit_b32 %[t], %[k1], %[k1], 19\n\t"
      "v_xor_b32 %[v1], %[t], %[v0]\n\t"
      TF_VRND(17) TF_VRND(6) TF_VRND(26)
      "v_add_u32 %[v0], %[v0], %[k1]\n\t"             // v0 += ks1
      "v_add3_u32 %[v1], %[v1], %[ks2], 1\n\t"        // v1 += ks2 + 1
      // group 2 (17,29,16,24)
      TF_VRND(15) TF_VRND(3) TF_VRND(16) TF_VRND(8)
      "v_add_u32 %[v0], %[v0], %[ks2]\n\t"            // v0 += ks2
      "v_add3_u32 %[v1], %[v1], %[k0], 2\n\t"         // v1 += ks0 + 2
      // group 3 (13,15,26,6)
      TF_VRND(19) TF_VRND(17) TF_VRND(6) TF_VRND(26)
      "v_add_u32 %[v0], %[v0], %[k0]\n\t"             // v0 += ks0
      "v_add3_u32 %[v1], %[v1], %[k1], 3\n\t"         // v1 += ks1 + 3
      // group 4 (17,29,16,24)
      TF_VRND(15) TF_VRND(3) TF_VRND(16) TF_VRND(8)
      "v_add_u32 %[v0], %[v0], %[k1]\n\t"             // v0 += ks1
      "v_add3_u32 %[v1], %[v1], %[ks2], 4\n\t"        // v1 += ks2 + 4
      // group 5 (13,15,26,6)
      TF_VRND(19) TF_VRND(17) TF_VRND(6) TF_VRND(26)
      // final: new k1 = v1 + old k0 + 5 (read k0 BEFORE overwrite), then k0
      "v_add3_u32 %[t], %[v1], %[k0], 5\n\t"
      "v_add_u32 %[k0], %[v0], %[ks2]\n\t"
      "v_mov_b32 %[k1], %[t]\n\t"
      : [k0] "+v"(k0), [k1] "+v"(k1),
        [v0] "=&v"(v0), [v1] "=&v"(v1), [t] "=&v"(t), [ks2] "=&v"(ks2));
}

// Per-lane C++ threefry — phase-2 draws. Verified R5/R6/R9; unchanged.
__device__ __forceinline__ void tf2x32(unsigned k0, unsigned k1,
                                       unsigned x0, unsigned x1,
                                       unsigned& y0, unsigned& y1) {
  const unsigned ks0 = k0, ks1 = k1, ks2 = k0 ^ k1 ^ 0x1BD11BDAu;
  unsigned v0 = x0 + ks0;
  unsigned v1 = x1 + ks1;
#define TF_R(r) do { v0 += v1; v1 = (v1 << (r)) | (v1 >> (32 - (r))); v1 ^= v0; } while (0)
  TF_R(13); TF_R(15); TF_R(26); TF_R(6);
  v0 += ks1; v1 += ks2 + 1u;
  TF_R(17); TF_R(29); TF_R(16); TF_R(24);
  v0 += ks2; v1 += ks0 + 2u;
  TF_R(13); TF_R(15); TF_R(26); TF_R(6);
  v0 += ks0; v1 += ks1 + 3u;
  TF_R(17); TF_R(29); TF_R(16); TF_R(24);
  v0 += ks1; v1 += ks2 + 4u;
  TF_R(13); TF_R(15); TF_R(26); TF_R(6);
  v0 += ks2; v1 += ks0 + 5u;
#undef TF_R
  y0 = v0; y1 = v1;
}

__global__ __launch_bounds__(64)
void span_mask_kernel(const int* __restrict__ x0tok,
                      const float* __restrict__ mask_prob,
                      int* __restrict__ out) {
  const int r = blockIdx.x;
  const int lane = threadIdx.x;

  __shared__ __align__(16) unsigned maskw[kWords];
  for (int i = lane; i < kWords; i += 64) maskw[i] = 0u;
  __syncthreads();

  const int target = (int)floorf(mask_prob[r] * 8192.0f);  // *2^13 exact
  const float Cf = -0.40546512603759765625f;  // f32(log1p(-f32(1/3))) exact

  unsigned key0 = 0u, key1 = 42u;  // jax.random.key(42)
  int cur = 0;

  for (int b = 0; b < kMaxBatches; ++b) {
    // ---- phase 1: 64 chain links (VALU asm); lane t captures key_{b*64+t} --
    unsigned mk0 = 0u, mk1 = 0u;
#pragma unroll 1
    for (int t = 0; t < kBatch; ++t) {
      const bool sel = (lane == t);
      mk0 = sel ? key0 : mk0;   // v_cmp + v_cndmask, v->v, off critical path
      mk1 = sel ? key1 : mk1;
      tf_link_valu(key0, key1); // key <- subkey 0 of split(key,3)
    }

    // ---- phase 2: per-lane draws for iteration b*64+lane -------------------
    unsigned ksA, ksB, klA, klB, k2A, k2B, d0, d1, e0, e1;
    tf2x32(mk0, mk1, 0u, 1u, ksA, ksB);        // ks = subkey 1
    tf2x32(mk0, mk1, 0u, 2u, klA, klB);        // kl = subkey 2
    tf2x32(ksA, ksB, 0u, 1u, k2A, k2B);        // k2 = split(ks,2)[1]
    tf2x32(k2A, k2B, 0u, (unsigned)r, d0, d1); // start bits
    tf2x32(klA, klB, 0u, (unsigned)r, e0, e1); // uniform bits
    const int start = (int)((d0 ^ d1) & 8191u);
    const unsigned ubits = e0 ^ e1;

    float f = __uint_as_float((ubits >> 9) | 0x3F800000u) - 1.0f;  // exact
    float val = __fadd_rn(__fmul_rn(f, (1.0f - 1e-7f)), 1e-7f);    // no FMA
    float u = fmaxf(1e-7f, val);
    float lf = (float)log((double)u);   // correctly-rounded f32 log
    float q = __fdiv_rn(lf, Cf);
    int geo = (int)floorf(q) + 1;       // 1..40
    int len = min(geo, kS - start);
    const int end = start + len;

    // ---- phase 3: optimistic apply; exact count from atomic returns --------
    // Single wave: DS ops execute in issue order; no barriers needed.
    uint4 pre = *(const uint4*)&maskw[4 * lane];  // pre-batch snapshot
    const int w0 = start >> 5, w1 = (end - 1) >> 5;  // <=3 words (len<=40)
    int d = 0;
#pragma unroll
    for (int k = 0; k < 3; ++k) {
      int w = w0 + k;
      if (w <= w1) {
        int lo = max(start - (w << 5), 0);
        int hi = min(end - (w << 5), 32);
        unsigned bits = (hi >= 32 ? 0xFFFFFFFFu : ((1u << hi) - 1u))
                        & (0xFFFFFFFFu << lo);
        unsigned old = atomicOr(&maskw[w], bits);
        d += __popc(bits & ~old);   // Σ over ops = |new union bits| exact
      }
    }
#pragma unroll
    for (int off = 1; off < 64; off <<= 1) d += __shfl_xor(d, off);
    const int newcur = cur + d;

    if (newcur < target) { cur = newcur; continue; }  // batch fully valid

    // ---- crossing batch: restore pre-state, exact serial replay ------------
    *(uint4*)&maskw[4 * lane] = pre;
#pragma unroll 1
    for (int i = 0; i < kBatch; ++i) {
      if (cur >= target) break;
      int st = __shfl(start, i);
      int en = __shfl(end, i);
      int iw0 = st >> 5, iw1 = (en - 1) >> 5;
      int dd = 0;
      int w = iw0 + lane;
      if (w <= iw1) {
        int lo = max(st - (w << 5), 0);
        int hi = min(en - (w << 5), 32);
        unsigned bits = (hi >= 32 ? 0xFFFFFFFFu : ((1u << hi) - 1u))
                        & (0xFFFFFFFFu << lo);
        unsigned old = maskw[w];
        maskw[w] = old | bits;
        dd = __popc(bits & ~old);
      }
      dd += __shfl_xor(dd, 1);
      dd += __shfl_xor(dd, 2);
      cur += __shfl(dd, 0);
    }
    break;  // row done
  }

  __syncthreads();

  // ---- epilogue: int4-vectorized writes of x_masked and mask ---------------
  const int base4 = r * (kS / 4);
  for (int i = lane; i < kS / 4; i += 64) {
    int4 tok = ((const int4*)x0tok)[base4 + i];
    unsigned nib = maskw[i >> 3] >> ((i & 7) * 4);
    int4 xm, mm;
    mm.x = (int)(nib & 1u);        xm.x = mm.x ? kMaskTok : tok.x;
    mm.y = (int)((nib >> 1) & 1u); xm.y = mm.y ? kMaskTok : tok.y;
    mm.z = (int)((nib >> 2) & 1u); xm.z = mm.z ? kMaskTok : tok.z;
    mm.w = (int)((nib >> 3) & 1u); xm.w = mm.w ? kMaskTok : tok.w;
    ((int4*)out)[base4 + i] = xm;
    ((int4*)out)[kB * (kS / 4) + base4 + i] = mm;
  }
}

extern "C" void kernel_launch(void* const* d_in, const int* in_sizes, int n_in,
                              void* d_out, int out_size, void* d_ws, size_t ws_size,
                              hipStream_t stream) {
  const int* x0 = (const int*)d_in[0];
  const float* mp = (const float*)d_in[1];
  int* out = (int*)d_out;
  hipLaunchKernelGGL(span_mask_kernel, dim3(kB), dim3(64), 0, stream,
                     x0, mp, out);
}

// Round 12
// 87.091 us; speedup vs baseline: 3.2230x; 2.0402x over previous
//
#include <hip/hip_runtime.h>

// Span masking — bit-exact JAX threefry2x32 stream (verified R5-R11).
// R12: the key chain depends ONLY on key(42) — it is a compile-time constant.
// Bake per-iteration derived keys (k2_t, kl_t) into a __constant__ table via
// chunked constexpr evaluation (8 x 256 iters, each ~166k constexpr steps,
// under clang's 1M limit). Kernel does ZERO serial chain work for t < 2048;
// runtime fallback (verified R11 walk) beyond the table, from the baked
// end-state. Per batch: 16B table load + 2 independent tf2x32 + log + the
// verified optimistic LDS apply.
//
// Stream (jax_threefry_partitionable=True):
//   split(key,n): keys[i] = (y0,y1) of tf(key,(0,i))
//   random_bits(key,32,(128,))[r] = y0^y1 of tf(key,(0,r))
//   _randint: (k1,k2)=split(key,2); span=2^13 -> start = bits(k2)[r] & 8191
//   _uniform: bits(key) directly
//   chain: key_{t+1} = tf(key_t,(0,0));  k2_t = tf(tf(key_t,(0,1)),(0,1));
//          kl_t = tf(key_t,(0,2));  key_0 = (0,42)

static constexpr int kB = 128;
static constexpr int kS = 8192;
static constexpr int kWords = kS / 32;   // 256
static constexpr int kMaskTok = 50256;
static constexpr int kBatch = 64;
static constexpr int kTab = 2048;        // precomputed iterations (need ~704)
static constexpr int kMaxBatches = 256;  // incl. fallback region (paranoia)

// ---------------- compile-time threefry ----------------
struct KeyPair { unsigned a, b; };

constexpr unsigned rotl_c(unsigned x, int r) {
  return (x << r) | (x >> (32 - r));
}

constexpr KeyPair tf_c(unsigned k0, unsigned k1, unsigned x0, unsigned x1) {
  unsigned ks[3] = {k0, k1, k0 ^ k1 ^ 0x1BD11BDAu};
  unsigned v0 = x0 + ks[0], v1 = x1 + ks[1];
  const int RA[4] = {13, 15, 26, 6};
  const int RB[4] = {17, 29, 16, 24};
  for (int g = 0; g < 5; ++g) {
    const int* r = (g & 1) ? RB : RA;
    for (int i = 0; i < 4; ++i) { v0 += v1; v1 = rotl_c(v1, r[i]); v1 ^= v0; }
    v0 += ks[(g + 1) % 3];
    v1 += ks[(g + 2) % 3] + (unsigned)(g + 1);
  }
  return {v0, v1};
}

struct alignas(16) Entry { unsigned k2a, k2b, kla, klb; };
static constexpr int kChunk = 256;
struct Chunk { Entry e[kChunk]; KeyPair end; };

constexpr Chunk make_chunk(KeyPair s) {
  Chunk c{};
  KeyPair key = s;
  for (int i = 0; i < kChunk; ++i) {
    KeyPair ks = tf_c(key.a, key.b, 0u, 1u);   // subkey 1 of split(key,3)
    KeyPair kl = tf_c(key.a, key.b, 0u, 2u);   // subkey 2
    KeyPair k2 = tf_c(ks.a, ks.b, 0u, 1u);     // split(ks,2)[1]
    c.e[i] = Entry{k2.a, k2.b, kl.a, kl.b};
    key = tf_c(key.a, key.b, 0u, 0u);          // chain link
  }
  c.end = key;
  return c;
}

// 8 separate constexpr evaluations (each under the step limit)
constexpr Chunk g_c0 = make_chunk(KeyPair{0u, 42u});
constexpr Chunk g_c1 = make_chunk(g_c0.end);
constexpr Chunk g_c2 = make_chunk(g_c1.end);
constexpr Chunk g_c3 = make_chunk(g_c2.end);
constexpr Chunk g_c4 = make_chunk(g_c3.end);
constexpr Chunk g_c5 = make_chunk(g_c4.end);
constexpr Chunk g_c6 = make_chunk(g_c5.end);
constexpr Chunk g_c7 = make_chunk(g_c6.end);

struct TabAll { Entry e[kTab]; };
constexpr TabAll make_all() {
  TabAll t{};
  const Chunk* cs[8] = {&g_c0, &g_c1, &g_c2, &g_c3,
                        &g_c4, &g_c5, &g_c6, &g_c7};
  for (int c = 0; c < 8; ++c)
    for (int i = 0; i < kChunk; ++i)
      t.e[c * kChunk + i] = cs[c]->e[i];
  return t;
}

__constant__ TabAll g_tab = make_all();
__constant__ KeyPair g_chain_end = g_c7.end;   // key state at iteration kTab

// ---------------- device threefry (verified R5-R11) ----------------
__device__ __forceinline__ void tf2x32(unsigned k0, unsigned k1,
                                       unsigned x0, unsigned x1,
                                       unsigned& y0, unsigned& y1) {
  const unsigned ks0 = k0, ks1 = k1, ks2 = k0 ^ k1 ^ 0x1BD11BDAu;
  unsigned v0 = x0 + ks0;
  unsigned v1 = x1 + ks1;
#define TF_R(r) do { v0 += v1; v1 = (v1 << (r)) | (v1 >> (32 - (r))); v1 ^= v0; } while (0)
  TF_R(13); TF_R(15); TF_R(26); TF_R(6);
  v0 += ks1; v1 += ks2 + 1u;
  TF_R(17); TF_R(29); TF_R(16); TF_R(24);
  v0 += ks2; v1 += ks0 + 2u;
  TF_R(13); TF_R(15); TF_R(26); TF_R(6);
  v0 += ks0; v1 += ks1 + 3u;
  TF_R(17); TF_R(29); TF_R(16); TF_R(24);
  v0 += ks1; v1 += ks2 + 4u;
  TF_R(13); TF_R(15); TF_R(26); TF_R(6);
  v0 += ks2; v1 += ks0 + 5u;
#undef TF_R
  y0 = v0; y1 = v1;
}

__global__ __launch_bounds__(64)
void span_mask_kernel(const int* __restrict__ x0tok,
                      const float* __restrict__ mask_prob,
                      int* __restrict__ out) {
  const int r = blockIdx.x;
  const int lane = threadIdx.x;

  __shared__ __align__(16) unsigned maskw[kWords];
  for (int i = lane; i < kWords; i += 64) maskw[i] = 0u;
  __syncthreads();

  const int target = (int)floorf(mask_prob[r] * 8192.0f);  // *2^13 exact
  const float Cf = -0.40546512603759765625f;  // f32(log1p(-f32(1/3))) exact

  int cur = 0;
  unsigned fb0 = 0u, fb1 = 0u;   // fallback chain state (iterations >= kTab)
  bool fb_init = false;

  for (int b = 0; b < kMaxBatches; ++b) {
    const int base = b * kBatch;

    // ---- phase 1+2a: per-iteration keys (table hit; chain gone) ----------
    unsigned k2A, k2B, klA, klB;
    if (base < kTab) {
      Entry en = g_tab.e[base + lane];
      k2A = en.k2a; k2B = en.k2b; klA = en.kla; klB = en.klb;
    } else {
      // fallback: runtime walk from the baked end-state (verified R11 path)
      if (!fb_init) { fb0 = g_chain_end.a; fb1 = g_chain_end.b; fb_init = true; }
      unsigned mk0 = 0u, mk1 = 0u;
#pragma unroll 1
      for (int t = 0; t < kBatch; ++t) {
        const bool sel = (lane == t);
        mk0 = sel ? fb0 : mk0;
        mk1 = sel ? fb1 : mk1;
        unsigned n0, n1;
        tf2x32(fb0, fb1, 0u, 0u, n0, n1);
        fb0 = n0; fb1 = n1;
      }
      unsigned ksA, ksB;
      tf2x32(mk0, mk1, 0u, 1u, ksA, ksB);
      tf2x32(mk0, mk1, 0u, 2u, klA, klB);
      tf2x32(ksA, ksB, 0u, 1u, k2A, k2B);
    }

    // ---- phase 2b: per-row draws (2 independent threefrys) ---------------
    unsigned d0, d1, e0, e1;
    tf2x32(k2A, k2B, 0u, (unsigned)r, d0, d1);  // start bits
    tf2x32(klA, klB, 0u, (unsigned)r, e0, e1);  // uniform bits
    const int start = (int)((d0 ^ d1) & 8191u);
    const unsigned ubits = e0 ^ e1;

    float f = __uint_as_float((ubits >> 9) | 0x3F800000u) - 1.0f;  // exact
    float val = __fadd_rn(__fmul_rn(f, (1.0f - 1e-7f)), 1e-7f);    // no FMA
    float u = fmaxf(1e-7f, val);
    float lf = (float)log((double)u);   // correctly-rounded f32 log
    float q = __fdiv_rn(lf, Cf);
    int geo = (int)floorf(q) + 1;       // 1..40
    int len = min(geo, kS - start);
    const int end = start + len;

    // ---- phase 3: optimistic apply; exact count from atomic returns ------
    // Single wave: DS ops execute in issue order; no barriers needed.
    uint4 pre = *(const uint4*)&maskw[4 * lane];  // pre-batch snapshot
    const int w0 = start >> 5, w1 = (end - 1) >> 5;  // <=3 words (len<=40)
    int d = 0;
#pragma unroll
    for (int k = 0; k < 3; ++k) {
      int w = w0 + k;
      if (w <= w1) {
        int lo = max(start - (w << 5), 0);
        int hi = min(end - (w << 5), 32);
        unsigned bits = (hi >= 32 ? 0xFFFFFFFFu : ((1u << hi) - 1u))
                        & (0xFFFFFFFFu << lo);
        unsigned old = atomicOr(&maskw[w], bits);
        d += __popc(bits & ~old);   // Σ over ops = |new union bits| exact
      }
    }
#pragma unroll
    for (int off = 1; off < 64; off <<= 1) d += __shfl_xor(d, off);
    const int newcur = cur + d;

    if (newcur < target) { cur = newcur; continue; }  // batch fully valid

    // ---- crossing batch: restore pre-state, exact serial replay ----------
    *(uint4*)&maskw[4 * lane] = pre;
#pragma unroll 1
    for (int i = 0; i < kBatch; ++i) {
      if (cur >= target) break;
      int st = __shfl(start, i);
      int en = __shfl(end, i);
      int iw0 = st >> 5, iw1 = (en - 1) >> 5;
      int dd = 0;
      int w = iw0 + lane;
      if (w <= iw1) {
        int lo = max(st - (w << 5), 0);
        int hi = min(en - (w << 5), 32);
        unsigned bits = (hi >= 32 ? 0xFFFFFFFFu : ((1u << hi) - 1u))
                        & (0xFFFFFFFFu << lo);
        unsigned old = maskw[w];
        maskw[w] = old | bits;
        dd = __popc(bits & ~old);
      }
      dd += __shfl_xor(dd, 1);
      dd += __shfl_xor(dd, 2);
      cur += __shfl(dd, 0);
    }
    break;  // row done
  }

  __syncthreads();

  // ---- epilogue: int4-vectorized writes of x_masked and mask -------------
  const int base4 = r * (kS / 4);
  for (int i = lane; i < kS / 4; i += 64) {
    int4 tok = ((const int4*)x0tok)[base4 + i];
    unsigned nib = maskw[i >> 3] >> ((i & 7) * 4);
    int4 xm, mm;
    mm.x = (int)(nib & 1u);        xm.x = mm.x ? kMaskTok : tok.x;
    mm.y = (int)((nib >> 1) & 1u); xm.y = mm.y ? kMaskTok : tok.y;
    mm.z = (int)((nib >> 2) & 1u); xm.z = mm.z ? kMaskTok : tok.z;
    mm.w = (int)((nib >> 3) & 1u); xm.w = mm.w ? kMaskTok : tok.w;
    ((int4*)out)[base4 + i] = xm;
    ((int4*)out)[kB * (kS / 4) + base4 + i] = mm;
  }
}

extern "C" void kernel_launch(void* const* d_in, const int* in_sizes, int n_in,
                              void* d_out, int out_size, void* d_ws, size_t ws_size,
                              hipStream_t stream) {
  const int* x0 = (const int*)d_in[0];
  const float* mp = (const float*)d_in[1];
  int* out = (int*)d_out;
  hipLaunchKernelGGL(span_mask_kernel, dim3(kB), dim3(64), 0, stream,
                     x0, mp, out);
}

// Round 13
// 79.782 us; speedup vs baseline: 3.5183x; 1.0916x over previous
//
#include <hip/hip_runtime.h>

// Span masking — bit-exact JAX threefry2x32 stream (verified R5-R12).
// R13: the per-iteration draws (start,len)_{t,r} depend only on (t,r) — no
// runtime data. Kernel 1 (draws_kernel) computes all t<2048, r<128 draws in
// parallel (throughput-bound; the serial-latency problem vanishes) into d_ws.
// Kernel 2 (span_mask_kernel) per batch: one u32 load (2-deep pipeline) + the
// verified optimistic LDS apply. Tier-3 runtime fallback beyond the table
// (verified R12 walk) keeps correctness independent of table size.
//
// Stream (jax_threefry_partitionable=True):
//   split(key,n): keys[i] = (y0,y1) of tf(key,(0,i))
//   random_bits(key,32,(128,))[r] = y0^y1 of tf(key,(0,r))
//   _randint: (k1,k2)=split(key,2); span=2^13 -> start = bits(k2)[r] & 8191
//   _uniform: bits(key) directly
//   chain: key_{t+1}=tf(key_t,(0,0)); k2_t=tf(tf(key_t,(0,1)),(0,1));
//          kl_t=tf(key_t,(0,2)); key_0=(0,42)

static constexpr int kB = 128;
static constexpr int kS = 8192;
static constexpr int kWords = kS / 32;   // 256
static constexpr int kMaskTok = 50256;
static constexpr int kBatch = 64;
static constexpr int kTab = 2048;        // precomputed iterations (need ~704)
static constexpr int kTabBatches = kTab / kBatch;  // 32
static constexpr int kMaxBatches = 256;  // incl. fallback region

// ---------------- compile-time threefry ----------------
struct KeyPair { unsigned a, b; };

constexpr unsigned rotl_c(unsigned x, int r) {
  return (x << r) | (x >> (32 - r));
}

constexpr KeyPair tf_c(unsigned k0, unsigned k1, unsigned x0, unsigned x1) {
  unsigned ks[3] = {k0, k1, k0 ^ k1 ^ 0x1BD11BDAu};
  unsigned v0 = x0 + ks[0], v1 = x1 + ks[1];
  const int RA[4] = {13, 15, 26, 6};
  const int RB[4] = {17, 29, 16, 24};
  for (int g = 0; g < 5; ++g) {
    const int* r = (g & 1) ? RB : RA;
    for (int i = 0; i < 4; ++i) { v0 += v1; v1 = rotl_c(v1, r[i]); v1 ^= v0; }
    v0 += ks[(g + 1) % 3];
    v1 += ks[(g + 2) % 3] + (unsigned)(g + 1);
  }
  return {v0, v1};
}

struct alignas(16) Entry { unsigned k2a, k2b, kla, klb; };
static constexpr int kChunk = 256;
struct Chunk { Entry e[kChunk]; KeyPair end; };

constexpr Chunk make_chunk(KeyPair s) {
  Chunk c{};
  KeyPair key = s;
  for (int i = 0; i < kChunk; ++i) {
    KeyPair ks = tf_c(key.a, key.b, 0u, 1u);   // subkey 1 of split(key,3)
    KeyPair kl = tf_c(key.a, key.b, 0u, 2u);   // subkey 2
    KeyPair k2 = tf_c(ks.a, ks.b, 0u, 1u);     // split(ks,2)[1]
    c.e[i] = Entry{k2.a, k2.b, kl.a, kl.b};
    key = tf_c(key.a, key.b, 0u, 0u);          // chain link
  }
  c.end = key;
  return c;
}

constexpr Chunk g_c0 = make_chunk(KeyPair{0u, 42u});
constexpr Chunk g_c1 = make_chunk(g_c0.end);
constexpr Chunk g_c2 = make_chunk(g_c1.end);
constexpr Chunk g_c3 = make_chunk(g_c2.end);
constexpr Chunk g_c4 = make_chunk(g_c3.end);
constexpr Chunk g_c5 = make_chunk(g_c4.end);
constexpr Chunk g_c6 = make_chunk(g_c5.end);
constexpr Chunk g_c7 = make_chunk(g_c6.end);

struct TabAll { Entry e[kTab]; };
constexpr TabAll make_all() {
  TabAll t{};
  const Chunk* cs[8] = {&g_c0, &g_c1, &g_c2, &g_c3,
                        &g_c4, &g_c5, &g_c6, &g_c7};
  for (int c = 0; c < 8; ++c)
    for (int i = 0; i < kChunk; ++i)
      t.e[c * kChunk + i] = cs[c]->e[i];
  return t;
}

__constant__ TabAll g_tab = make_all();
__constant__ KeyPair g_chain_end = g_c7.end;   // key state at iteration kTab

// ---------------- device threefry (verified R5-R12) ----------------
__device__ __forceinline__ void tf2x32(unsigned k0, unsigned k1,
                                       unsigned x0, unsigned x1,
                                       unsigned& y0, unsigned& y1) {
  const unsigned ks0 = k0, ks1 = k1, ks2 = k0 ^ k1 ^ 0x1BD11BDAu;
  unsigned v0 = x0 + ks0;
  unsigned v1 = x1 + ks1;
#define TF_R(r) do { v0 += v1; v1 = (v1 << (r)) | (v1 >> (32 - (r))); v1 ^= v0; } while (0)
  TF_R(13); TF_R(15); TF_R(26); TF_R(6);
  v0 += ks1; v1 += ks2 + 1u;
  TF_R(17); TF_R(29); TF_R(16); TF_R(24);
  v0 += ks2; v1 += ks0 + 2u;
  TF_R(13); TF_R(15); TF_R(26); TF_R(6);
  v0 += ks0; v1 += ks1 + 3u;
  TF_R(17); TF_R(29); TF_R(16); TF_R(24);
  v0 += ks1; v1 += ks2 + 4u;
  TF_R(13); TF_R(15); TF_R(26); TF_R(6);
  v0 += ks2; v1 += ks0 + 5u;
#undef TF_R
  y0 = v0; y1 = v1;
}

// Full verified draw path: (k2,kl,r) -> packed start|len<<16. Byte-identical
// math to R12 (absmax 0): xor-fold bits, uniform, f64 log, f32 div, floor+1.
__device__ __forceinline__ unsigned draw_pack(unsigned k2A, unsigned k2B,
                                              unsigned klA, unsigned klB,
                                              int r) {
  unsigned d0, d1, e0, e1;
  tf2x32(k2A, k2B, 0u, (unsigned)r, d0, d1);  // start bits
  tf2x32(klA, klB, 0u, (unsigned)r, e0, e1);  // uniform bits
  const int start = (int)((d0 ^ d1) & 8191u);
  const unsigned ubits = e0 ^ e1;
  float f = __uint_as_float((ubits >> 9) | 0x3F800000u) - 1.0f;  // exact
  float val = __fadd_rn(__fmul_rn(f, (1.0f - 1e-7f)), 1e-7f);    // no FMA
  float u = fmaxf(1e-7f, val);
  float lf = (float)log((double)u);   // correctly-rounded f32 log
  float q = __fdiv_rn(lf, -0.40546512603759765625f);
  int geo = (int)floorf(q) + 1;       // 1..40
  int len = min(geo, kS - start);     // 1..40
  return (unsigned)start | ((unsigned)len << 16);
}

// ---------------- kernel 1: all draws, fully parallel ----------------
__global__ __launch_bounds__(256)
void draws_kernel(unsigned* __restrict__ pk) {
  const int g = blockIdx.x * 256 + threadIdx.x;   // 0 .. 128*2048-1
  const int t = g & (kTab - 1);
  const int r = g >> 11;
  Entry e = g_tab.e[t];
  pk[r * kTab + t] = draw_pack(e.k2a, e.k2b, e.kla, e.klb, r);
}

// ---------------- kernel 2: per-row span walk ----------------
__global__ __launch_bounds__(64)
void span_mask_kernel(const int* __restrict__ x0tok,
                      const float* __restrict__ mask_prob,
                      int* __restrict__ out,
                      const unsigned* __restrict__ pk) {
  const int r = blockIdx.x;
  const int lane = threadIdx.x;

  __shared__ __align__(16) unsigned maskw[kWords];
  for (int i = lane; i < kWords; i += 64) maskw[i] = 0u;
  __syncthreads();

  const int target = (int)floorf(mask_prob[r] * 8192.0f);  // *2^13 exact

  const unsigned* pkr = pk + r * kTab;
  unsigned nxt0 = pkr[lane];        // batch 0 (issued now; used later)
  unsigned nxt1 = pkr[64 + lane];   // batch 1

  int cur = 0;
  unsigned fb0 = 0u, fb1 = 0u;   // fallback chain state (iterations >= kTab)
  bool fb_init = false;

  for (int b = 0; b < kMaxBatches; ++b) {
    // ---- per-iteration draw for iteration b*64+lane -----------------------
    unsigned pkc;
    if (b < kTabBatches) {
      pkc = nxt0;
      nxt0 = nxt1;
      if (b + 2 < kTabBatches) nxt1 = pkr[(b + 2) * 64 + lane];
    } else {
      // tier-3 fallback: runtime walk from baked end-state (verified R12)
      if (!fb_init) { fb0 = g_chain_end.a; fb1 = g_chain_end.b; fb_init = true; }
      unsigned mk0 = 0u, mk1 = 0u;
#pragma unroll 1
      for (int t = 0; t < kBatch; ++t) {
        const bool sel = (lane == t);
        mk0 = sel ? fb0 : mk0;
        mk1 = sel ? fb1 : mk1;
        unsigned n0, n1;
        tf2x32(fb0, fb1, 0u, 0u, n0, n1);
        fb0 = n0; fb1 = n1;
      }
      unsigned ksA, ksB, klA, klB, k2A, k2B;
      tf2x32(mk0, mk1, 0u, 1u, ksA, ksB);
      tf2x32(mk0, mk1, 0u, 2u, klA, klB);
      tf2x32(ksA, ksB, 0u, 1u, k2A, k2B);
      pkc = draw_pack(k2A, k2B, klA, klB, r);
    }
    const int start = (int)(pkc & 8191u);
    const int len = (int)(pkc >> 16);
    const int end = start + len;

    // ---- phase 3: optimistic apply; exact count from atomic returns ------
    // Single wave: DS ops execute in issue order; no barriers needed.
    uint4 pre = *(const uint4*)&maskw[4 * lane];  // pre-batch snapshot
    const int w0 = start >> 5, w1 = (end - 1) >> 5;  // <=3 words (len<=40)
    int d = 0;
#pragma unroll
    for (int k = 0; k < 3; ++k) {
      int w = w0 + k;
      if (w <= w1) {
        int lo = max(start - (w << 5), 0);
        int hi = min(end - (w << 5), 32);
        unsigned bits = (hi >= 32 ? 0xFFFFFFFFu : ((1u << hi) - 1u))
                        & (0xFFFFFFFFu << lo);
        unsigned old = atomicOr(&maskw[w], bits);
        d += __popc(bits & ~old);   // Σ over ops = |new union bits| exact
      }
    }
#pragma unroll
    for (int off = 1; off < 64; off <<= 1) d += __shfl_xor(d, off);
    const int newcur = cur + d;

    if (newcur < target) { cur = newcur; continue; }  // batch fully valid

    // ---- crossing batch: restore pre-state, exact serial replay ----------
    *(uint4*)&maskw[4 * lane] = pre;
#pragma unroll 1
    for (int i = 0; i < kBatch; ++i) {
      if (cur >= target) break;
      int st = __shfl(start, i);
      int en = __shfl(end, i);
      int iw0 = st >> 5, iw1 = (en - 1) >> 5;
      int dd = 0;
      int w = iw0 + lane;
      if (w <= iw1) {
        int lo = max(st - (w << 5), 0);
        int hi = min(en - (w << 5), 32);
        unsigned bits = (hi >= 32 ? 0xFFFFFFFFu : ((1u << hi) - 1u))
                        & (0xFFFFFFFFu << lo);
        unsigned old = maskw[w];
        maskw[w] = old | bits;
        dd = __popc(bits & ~old);
      }
      dd += __shfl_xor(dd, 1);
      dd += __shfl_xor(dd, 2);
      cur += __shfl(dd, 0);
    }
    break;  // row done
  }

  __syncthreads();

  // ---- epilogue: 8-deep pipelined int4 writes of x_masked and mask -------
  const int base4 = r * (kS / 4);
#pragma unroll
  for (int g8 = 0; g8 < 4; ++g8) {
    int4 tok[8];
#pragma unroll
    for (int k = 0; k < 8; ++k)
      tok[k] = ((const int4*)x0tok)[base4 + (g8 * 8 + k) * 64 + lane];
#pragma unroll
    for (int k = 0; k < 8; ++k) {
      const int i = (g8 * 8 + k) * 64 + lane;
      unsigned nib = maskw[i >> 3] >> ((i & 7) * 4);
      int4 xm, mm;
      mm.x = (int)(nib & 1u);        xm.x = mm.x ? kMaskTok : tok[k].x;
      mm.y = (int)((nib >> 1) & 1u); xm.y = mm.y ? kMaskTok : tok[k].y;
      mm.z = (int)((nib >> 2) & 1u); xm.z = mm.z ? kMaskTok : tok[k].z;
      mm.w = (int)((nib >> 3) & 1u); xm.w = mm.w ? kMaskTok : tok[k].w;
      ((int4*)out)[base4 + i] = xm;
      ((int4*)out)[kB * (kS / 4) + base4 + i] = mm;
    }
  }
}

extern "C" void kernel_launch(void* const* d_in, const int* in_sizes, int n_in,
                              void* d_out, int out_size, void* d_ws, size_t ws_size,
                              hipStream_t stream) {
  const int* x0 = (const int*)d_in[0];
  const float* mp = (const float*)d_in[1];
  int* out = (int*)d_out;
  unsigned* pk = (unsigned*)d_ws;   // 128*2048*4 B = 1 MB of workspace

  hipLaunchKernelGGL(draws_kernel, dim3(kB * kTab / 256), dim3(256), 0, stream,
                     pk);
  hipLaunchKernelGGL(span_mask_kernel, dim3(kB), dim3(64), 0, stream,
                     x0, mp, out, pk);
}

// Round 14
// 79.000 us; speedup vs baseline: 3.5531x; 1.0099x over previous
//
#include <hip/hip_runtime.h>

// Span masking — bit-exact JAX threefry2x32 stream (verified R5-R13).
// R14: single kernel. Per block (row): [prelude, 256 thr] compute all 2048
// per-iteration draws (start|len<<16) into LDS — fully parallel, kills R13's
// cross-XCD pk round-trip and the second launch; [walk, wave 0] verified
// optimistic batch apply + exact replay on the crossing batch, draws read
// from LDS; [epilogue, 256 thr] int4 masked writes (4x parallelism of R13).
//
// Stream (jax_threefry_partitionable=True):
//   split(key,n): keys[i] = (y0,y1) of tf(key,(0,i))
//   random_bits(key,32,(128,))[r] = y0^y1 of tf(key,(0,r))
//   _randint: (k1,k2)=split(key,2); span=2^13 -> start = bits(k2)[r] & 8191
//   _uniform: bits(key) directly
//   chain: key_{t+1}=tf(key_t,(0,0)); k2_t=tf(tf(key_t,(0,1)),(0,1));
//          kl_t=tf(key_t,(0,2)); key_0=(0,42)

static constexpr int kB = 128;
static constexpr int kS = 8192;
static constexpr int kWords = kS / 32;   // 256
static constexpr int kMaskTok = 50256;
static constexpr int kBatch = 64;
static constexpr int kTab = 2048;        // precomputed iterations (need ~704)
static constexpr int kTabBatches = kTab / kBatch;  // 32
static constexpr int kMaxBatches = 256;  // incl. fallback region

// ---------------- compile-time threefry ----------------
struct KeyPair { unsigned a, b; };

constexpr unsigned rotl_c(unsigned x, int r) {
  return (x << r) | (x >> (32 - r));
}

constexpr KeyPair tf_c(unsigned k0, unsigned k1, unsigned x0, unsigned x1) {
  unsigned ks[3] = {k0, k1, k0 ^ k1 ^ 0x1BD11BDAu};
  unsigned v0 = x0 + ks[0], v1 = x1 + ks[1];
  const int RA[4] = {13, 15, 26, 6};
  const int RB[4] = {17, 29, 16, 24};
  for (int g = 0; g < 5; ++g) {
    const int* r = (g & 1) ? RB : RA;
    for (int i = 0; i < 4; ++i) { v0 += v1; v1 = rotl_c(v1, r[i]); v1 ^= v0; }
    v0 += ks[(g + 1) % 3];
    v1 += ks[(g + 2) % 3] + (unsigned)(g + 1);
  }
  return {v0, v1};
}

struct alignas(16) Entry { unsigned k2a, k2b, kla, klb; };
static constexpr int kChunk = 256;
struct Chunk { Entry e[kChunk]; KeyPair end; };

constexpr Chunk make_chunk(KeyPair s) {
  Chunk c{};
  KeyPair key = s;
  for (int i = 0; i < kChunk; ++i) {
    KeyPair ks = tf_c(key.a, key.b, 0u, 1u);   // subkey 1 of split(key,3)
    KeyPair kl = tf_c(key.a, key.b, 0u, 2u);   // subkey 2
    KeyPair k2 = tf_c(ks.a, ks.b, 0u, 1u);     // split(ks,2)[1]
    c.e[i] = Entry{k2.a, k2.b, kl.a, kl.b};
    key = tf_c(key.a, key.b, 0u, 0u);          // chain link
  }
  c.end = key;
  return c;
}

constexpr Chunk g_c0 = make_chunk(KeyPair{0u, 42u});
constexpr Chunk g_c1 = make_chunk(g_c0.end);
constexpr Chunk g_c2 = make_chunk(g_c1.end);
constexpr Chunk g_c3 = make_chunk(g_c2.end);
constexpr Chunk g_c4 = make_chunk(g_c3.end);
constexpr Chunk g_c5 = make_chunk(g_c4.end);
constexpr Chunk g_c6 = make_chunk(g_c5.end);
constexpr Chunk g_c7 = make_chunk(g_c6.end);

struct TabAll { Entry e[kTab]; };
constexpr TabAll make_all() {
  TabAll t{};
  const Chunk* cs[8] = {&g_c0, &g_c1, &g_c2, &g_c3,
                        &g_c4, &g_c5, &g_c6, &g_c7};
  for (int c = 0; c < 8; ++c)
    for (int i = 0; i < kChunk; ++i)
      t.e[c * kChunk + i] = cs[c]->e[i];
  return t;
}

__constant__ TabAll g_tab = make_all();
__constant__ KeyPair g_chain_end = g_c7.end;   // key state at iteration kTab

// ---------------- device threefry (verified R5-R13) ----------------
__device__ __forceinline__ void tf2x32(unsigned k0, unsigned k1,
                                       unsigned x0, unsigned x1,
                                       unsigned& y0, unsigned& y1) {
  const unsigned ks0 = k0, ks1 = k1, ks2 = k0 ^ k1 ^ 0x1BD11BDAu;
  unsigned v0 = x0 + ks0;
  unsigned v1 = x1 + ks1;
#define TF_R(r) do { v0 += v1; v1 = (v1 << (r)) | (v1 >> (32 - (r))); v1 ^= v0; } while (0)
  TF_R(13); TF_R(15); TF_R(26); TF_R(6);
  v0 += ks1; v1 += ks2 + 1u;
  TF_R(17); TF_R(29); TF_R(16); TF_R(24);
  v0 += ks2; v1 += ks0 + 2u;
  TF_R(13); TF_R(15); TF_R(26); TF_R(6);
  v0 += ks0; v1 += ks1 + 3u;
  TF_R(17); TF_R(29); TF_R(16); TF_R(24);
  v0 += ks1; v1 += ks2 + 4u;
  TF_R(13); TF_R(15); TF_R(26); TF_R(6);
  v0 += ks2; v1 += ks0 + 5u;
#undef TF_R
  y0 = v0; y1 = v1;
}

// Full verified draw path: (k2,kl,r) -> packed start|len<<16 (R13, absmax 0).
__device__ __forceinline__ unsigned draw_pack(unsigned k2A, unsigned k2B,
                                              unsigned klA, unsigned klB,
                                              int r) {
  unsigned d0, d1, e0, e1;
  tf2x32(k2A, k2B, 0u, (unsigned)r, d0, d1);  // start bits
  tf2x32(klA, klB, 0u, (unsigned)r, e0, e1);  // uniform bits
  const int start = (int)((d0 ^ d1) & 8191u);
  const unsigned ubits = e0 ^ e1;
  float f = __uint_as_float((ubits >> 9) | 0x3F800000u) - 1.0f;  // exact
  float val = __fadd_rn(__fmul_rn(f, (1.0f - 1e-7f)), 1e-7f);    // no FMA
  float u = fmaxf(1e-7f, val);
  float lf = (float)log((double)u);   // correctly-rounded f32 log
  float q = __fdiv_rn(lf, -0.40546512603759765625f);
  int geo = (int)floorf(q) + 1;       // 1..40
  int len = min(geo, kS - start);     // 1..40
  return (unsigned)start | ((unsigned)len << 16);
}

__global__ __launch_bounds__(256)
void span_mask_kernel(const int* __restrict__ x0tok,
                      const float* __restrict__ mask_prob,
                      int* __restrict__ out) {
  const int r = blockIdx.x;
  const int tid = threadIdx.x;

  __shared__ __align__(16) unsigned maskw[kWords];
  __shared__ unsigned dtab[kTab];   // this row's draws, start|len<<16

  for (int i = tid; i < kWords; i += 256) maskw[i] = 0u;

  // ---- prelude: all 2048 draws for this row, fully parallel (8/thread) ----
#pragma unroll
  for (int j = 0; j < kTab / 256; ++j) {
    const int t = j * 256 + tid;
    Entry e = g_tab.e[t];
    dtab[t] = draw_pack(e.k2a, e.k2b, e.kla, e.klb, r);
  }
  __syncthreads();

  // ---- walk: wave 0 only (verified batch apply + exact replay) ------------
  if (tid < 64) {
    const int lane = tid;
    const int target = (int)floorf(mask_prob[r] * 8192.0f);  // *2^13 exact

    int cur = 0;
    unsigned fb0 = 0u, fb1 = 0u;   // fallback chain state (iters >= kTab)
    bool fb_init = false;
    unsigned nxt = dtab[lane];     // batch-0 draw, prefetched

    for (int b = 0; b < kMaxBatches; ++b) {
      unsigned pkc;
      if (b < kTabBatches) {
        pkc = nxt;
        if (b + 1 < kTabBatches) nxt = dtab[(b + 1) * 64 + lane];
      } else {
        // tier-3 fallback: runtime walk from baked end-state (verified R12)
        if (!fb_init) { fb0 = g_chain_end.a; fb1 = g_chain_end.b; fb_init = true; }
        unsigned mk0 = 0u, mk1 = 0u;
#pragma unroll 1
        for (int t = 0; t < kBatch; ++t) {
          const bool sel = (lane == t);
          mk0 = sel ? fb0 : mk0;
          mk1 = sel ? fb1 : mk1;
          unsigned n0, n1;
          tf2x32(fb0, fb1, 0u, 0u, n0, n1);
          fb0 = n0; fb1 = n1;
        }
        unsigned ksA, ksB, klA, klB, k2A, k2B;
        tf2x32(mk0, mk1, 0u, 1u, ksA, ksB);
        tf2x32(mk0, mk1, 0u, 2u, klA, klB);
        tf2x32(ksA, ksB, 0u, 1u, k2A, k2B);
        pkc = draw_pack(k2A, k2B, klA, klB, r);
      }
      const int start = (int)(pkc & 8191u);
      const int end = start + (int)(pkc >> 16);

      // optimistic apply; exact count from atomic returns (single wave:
      // DS ops execute in issue order; no barriers needed)
      uint4 pre = *(const uint4*)&maskw[4 * lane];  // pre-batch snapshot
      const int w0 = start >> 5, w1 = (end - 1) >> 5;  // <=3 words (len<=40)
      int d = 0;
#pragma unroll
      for (int k = 0; k < 3; ++k) {
        int w = w0 + k;
        if (w <= w1) {
          int lo = max(start - (w << 5), 0);
          int hi = min(end - (w << 5), 32);
          unsigned bits = (hi >= 32 ? 0xFFFFFFFFu : ((1u << hi) - 1u))
                          & (0xFFFFFFFFu << lo);
          unsigned old = atomicOr(&maskw[w], bits);
          d += __popc(bits & ~old);   // Σ over ops = |new union bits| exact
        }
      }
#pragma unroll
      for (int off = 1; off < 64; off <<= 1) d += __shfl_xor(d, off);
      const int newcur = cur + d;

      if (newcur < target) { cur = newcur; continue; }  // batch fully valid

      // crossing batch: restore pre-state, exact serial replay
      *(uint4*)&maskw[4 * lane] = pre;
#pragma unroll 1
      for (int i = 0; i < kBatch; ++i) {
        if (cur >= target) break;
        int st = __shfl(start, i);
        int en = __shfl(end, i);
        int iw0 = st >> 5, iw1 = (en - 1) >> 5;
        int dd = 0;
        int w = iw0 + lane;
        if (w <= iw1) {
          int lo = max(st - (w << 5), 0);
          int hi = min(en - (w << 5), 32);
          unsigned bits = (hi >= 32 ? 0xFFFFFFFFu : ((1u << hi) - 1u))
                          & (0xFFFFFFFFu << lo);
          unsigned old = maskw[w];
          maskw[w] = old | bits;
          dd = __popc(bits & ~old);
        }
        dd += __shfl_xor(dd, 1);
        dd += __shfl_xor(dd, 2);
        cur += __shfl(dd, 0);
      }
      break;  // row done
    }
  }

  __syncthreads();  // waves 1-3 waited here during the walk

  // ---- epilogue: 4-wave, 8-deep pipelined int4 writes ---------------------
  const int base4 = r * (kS / 4);   // 2048 int4 per row; 8 per thread
  int4 tok[8];
#pragma unroll
  for (int k = 0; k < 8; ++k)
    tok[k] = ((const int4*)x0tok)[base4 + k * 256 + tid];
#pragma unroll
  for (int k = 0; k < 8; ++k) {
    const int i = k * 256 + tid;
    unsigned nib = maskw[i >> 3] >> ((i & 7) * 4);
    int4 xm, mm;
    mm.x = (int)(nib & 1u);        xm.x = mm.x ? kMaskTok : tok[k].x;
    mm.y = (int)((nib >> 1) & 1u); xm.y = mm.y ? kMaskTok : tok[k].y;
    mm.z = (int)((nib >> 2) & 1u); xm.z = mm.z ? kMaskTok : tok[k].z;
    mm.w = (int)((nib >> 3) & 1u); xm.w = mm.w ? kMaskTok : tok[k].w;
    ((int4*)out)[base4 + i] = xm;
    ((int4*)out)[kB * (kS / 4) + base4 + i] = mm;
  }
}

extern "C" void kernel_launch(void* const* d_in, const int* in_sizes, int n_in,
                              void* d_out, int out_size, void* d_ws, size_t ws_size,
                              hipStream_t stream) {
  const int* x0 = (const int*)d_in[0];
  const float* mp = (const float*)d_in[1];
  int* out = (int*)d_out;
  hipLaunchKernelGGL(span_mask_kernel, dim3(kB), dim3(256), 0, stream,
                     x0, mp, out);
}

// Round 15
// 69.220 us; speedup vs baseline: 4.0551x; 1.1413x over previous
//
#include <hip/hip_runtime.h>

// Span masking — bit-exact JAX threefry2x32 stream (verified R5-R14).
// R15: crossing-batch resolution via exact BINARY SEARCH (6 probes, each a
// lane<mid optimistic apply + exact count — the primitive verified since R12)
// replacing the ~11us 64-iteration serial replay. Epilogue token loads issued
// at kernel start so their HBM latency hides under prelude+walk.
//
// Stream (jax_threefry_partitionable=True):
//   split(key,n): keys[i] = (y0,y1) of tf(key,(0,i))
//   random_bits(key,32,(128,))[r] = y0^y1 of tf(key,(0,r))
//   _randint: (k1,k2)=split(key,2); span=2^13 -> start = bits(k2)[r] & 8191
//   _uniform: bits(key) directly
//   chain: key_{t+1}=tf(key_t,(0,0)); k2_t=tf(tf(key_t,(0,1)),(0,1));
//          kl_t=tf(key_t,(0,2)); key_0=(0,42)

static constexpr int kB = 128;
static constexpr int kS = 8192;
static constexpr int kWords = kS / 32;   // 256
static constexpr int kMaskTok = 50256;
static constexpr int kBatch = 64;
static constexpr int kTab = 2048;        // precomputed iterations (need ~704)
static constexpr int kTabBatches = kTab / kBatch;  // 32
static constexpr int kMaxBatches = 256;  // incl. fallback region

// ---------------- compile-time threefry ----------------
struct KeyPair { unsigned a, b; };

constexpr unsigned rotl_c(unsigned x, int r) {
  return (x << r) | (x >> (32 - r));
}

constexpr KeyPair tf_c(unsigned k0, unsigned k1, unsigned x0, unsigned x1) {
  unsigned ks[3] = {k0, k1, k0 ^ k1 ^ 0x1BD11BDAu};
  unsigned v0 = x0 + ks[0], v1 = x1 + ks[1];
  const int RA[4] = {13, 15, 26, 6};
  const int RB[4] = {17, 29, 16, 24};
  for (int g = 0; g < 5; ++g) {
    const int* r = (g & 1) ? RB : RA;
    for (int i = 0; i < 4; ++i) { v0 += v1; v1 = rotl_c(v1, r[i]); v1 ^= v0; }
    v0 += ks[(g + 1) % 3];
    v1 += ks[(g + 2) % 3] + (unsigned)(g + 1);
  }
  return {v0, v1};
}

struct alignas(16) Entry { unsigned k2a, k2b, kla, klb; };
static constexpr int kChunk = 256;
struct Chunk { Entry e[kChunk]; KeyPair end; };

constexpr Chunk make_chunk(KeyPair s) {
  Chunk c{};
  KeyPair key = s;
  for (int i = 0; i < kChunk; ++i) {
    KeyPair ks = tf_c(key.a, key.b, 0u, 1u);   // subkey 1 of split(key,3)
    KeyPair kl = tf_c(key.a, key.b, 0u, 2u);   // subkey 2
    KeyPair k2 = tf_c(ks.a, ks.b, 0u, 1u);     // split(ks,2)[1]
    c.e[i] = Entry{k2.a, k2.b, kl.a, kl.b};
    key = tf_c(key.a, key.b, 0u, 0u);          // chain link
  }
  c.end = key;
  return c;
}

constexpr Chunk g_c0 = make_chunk(KeyPair{0u, 42u});
constexpr Chunk g_c1 = make_chunk(g_c0.end);
constexpr Chunk g_c2 = make_chunk(g_c1.end);
constexpr Chunk g_c3 = make_chunk(g_c2.end);
constexpr Chunk g_c4 = make_chunk(g_c3.end);
constexpr Chunk g_c5 = make_chunk(g_c4.end);
constexpr Chunk g_c6 = make_chunk(g_c5.end);
constexpr Chunk g_c7 = make_chunk(g_c6.end);

struct TabAll { Entry e[kTab]; };
constexpr TabAll make_all() {
  TabAll t{};
  const Chunk* cs[8] = {&g_c0, &g_c1, &g_c2, &g_c3,
                        &g_c4, &g_c5, &g_c6, &g_c7};
  for (int c = 0; c < 8; ++c)
    for (int i = 0; i < kChunk; ++i)
      t.e[c * kChunk + i] = cs[c]->e[i];
  return t;
}

__constant__ TabAll g_tab = make_all();
__constant__ KeyPair g_chain_end = g_c7.end;   // key state at iteration kTab

// ---------------- device threefry (verified R5-R14) ----------------
__device__ __forceinline__ void tf2x32(unsigned k0, unsigned k1,
                                       unsigned x0, unsigned x1,
                                       unsigned& y0, unsigned& y1) {
  const unsigned ks0 = k0, ks1 = k1, ks2 = k0 ^ k1 ^ 0x1BD11BDAu;
  unsigned v0 = x0 + ks0;
  unsigned v1 = x1 + ks1;
#define TF_R(r) do { v0 += v1; v1 = (v1 << (r)) | (v1 >> (32 - (r))); v1 ^= v0; } while (0)
  TF_R(13); TF_R(15); TF_R(26); TF_R(6);
  v0 += ks1; v1 += ks2 + 1u;
  TF_R(17); TF_R(29); TF_R(16); TF_R(24);
  v0 += ks2; v1 += ks0 + 2u;
  TF_R(13); TF_R(15); TF_R(26); TF_R(6);
  v0 += ks0; v1 += ks1 + 3u;
  TF_R(17); TF_R(29); TF_R(16); TF_R(24);
  v0 += ks1; v1 += ks2 + 4u;
  TF_R(13); TF_R(15); TF_R(26); TF_R(6);
  v0 += ks2; v1 += ks0 + 5u;
#undef TF_R
  y0 = v0; y1 = v1;
}

// Full verified draw path: (k2,kl,r) -> packed start|len<<16 (R13, absmax 0).
__device__ __forceinline__ unsigned draw_pack(unsigned k2A, unsigned k2B,
                                              unsigned klA, unsigned klB,
                                              int r) {
  unsigned d0, d1, e0, e1;
  tf2x32(k2A, k2B, 0u, (unsigned)r, d0, d1);  // start bits
  tf2x32(klA, klB, 0u, (unsigned)r, e0, e1);  // uniform bits
  const int start = (int)((d0 ^ d1) & 8191u);
  const unsigned ubits = e0 ^ e1;
  float f = __uint_as_float((ubits >> 9) | 0x3F800000u) - 1.0f;  // exact
  float val = __fadd_rn(__fmul_rn(f, (1.0f - 1e-7f)), 1e-7f);    // no FMA
  float u = fmaxf(1e-7f, val);
  float lf = (float)log((double)u);   // correctly-rounded f32 log
  float q = __fdiv_rn(lf, -0.40546512603759765625f);
  int geo = (int)floorf(q) + 1;       // 1..40
  int len = min(geo, kS - start);     // 1..40
  return (unsigned)start | ((unsigned)len << 16);
}

// Span i's bit pattern within word w (w absolute), given [start,end).
__device__ __forceinline__ unsigned span_bits(int start, int end, int w) {
  int lo = max(start - (w << 5), 0);
  int hi = min(end - (w << 5), 32);
  return (hi >= 32 ? 0xFFFFFFFFu : ((1u << hi) - 1u)) & (0xFFFFFFFFu << lo);
}

__global__ __launch_bounds__(256)
void span_mask_kernel(const int* __restrict__ x0tok,
                      const float* __restrict__ mask_prob,
                      int* __restrict__ out) {
  const int r = blockIdx.x;
  const int tid = threadIdx.x;

  __shared__ __align__(16) unsigned maskw[kWords];
  __shared__ unsigned dtab[kTab];   // this row's draws, start|len<<16

  // ---- epilogue loads issued FIRST: latency hides under prelude+walk ------
  const int base4 = r * (kS / 4);   // 2048 int4 per row; 8 per thread
  int4 tok[8];
#pragma unroll
  for (int k = 0; k < 8; ++k)
    tok[k] = ((const int4*)x0tok)[base4 + k * 256 + tid];

  for (int i = tid; i < kWords; i += 256) maskw[i] = 0u;

  // ---- prelude: all 2048 draws for this row, fully parallel (8/thread) ----
#pragma unroll
  for (int j = 0; j < kTab / 256; ++j) {
    const int t = j * 256 + tid;
    Entry e = g_tab.e[t];
    dtab[t] = draw_pack(e.k2a, e.k2b, e.kla, e.klb, r);
  }
  __syncthreads();

  // ---- walk: wave 0 only (verified batch apply; binary-search crossing) ---
  if (tid < 64) {
    const int lane = tid;
    const int target = (int)floorf(mask_prob[r] * 8192.0f);  // *2^13 exact

    int cur = 0;
    unsigned fb0 = 0u, fb1 = 0u;   // fallback chain state (iters >= kTab)
    bool fb_init = false;
    unsigned nxt = dtab[lane];     // batch-0 draw, prefetched

    for (int b = 0; b < kMaxBatches; ++b) {
      unsigned pkc;
      if (b < kTabBatches) {
        pkc = nxt;
        if (b + 1 < kTabBatches) nxt = dtab[(b + 1) * 64 + lane];
      } else {
        // tier-3 fallback: runtime walk from baked end-state (verified R12)
        if (!fb_init) { fb0 = g_chain_end.a; fb1 = g_chain_end.b; fb_init = true; }
        unsigned mk0 = 0u, mk1 = 0u;
#pragma unroll 1
        for (int t = 0; t < kBatch; ++t) {
          const bool sel = (lane == t);
          mk0 = sel ? fb0 : mk0;
          mk1 = sel ? fb1 : mk1;
          unsigned n0, n1;
          tf2x32(fb0, fb1, 0u, 0u, n0, n1);
          fb0 = n0; fb1 = n1;
        }
        unsigned ksA, ksB, klA, klB, k2A, k2B;
        tf2x32(mk0, mk1, 0u, 1u, ksA, ksB);
        tf2x32(mk0, mk1, 0u, 2u, klA, klB);
        tf2x32(ksA, ksB, 0u, 1u, k2A, k2B);
        pkc = draw_pack(k2A, k2B, klA, klB, r);
      }
      const int start = (int)(pkc & 8191u);
      const int end = start + (int)(pkc >> 16);
      const int w0 = start >> 5, w1 = (end - 1) >> 5;  // <=3 words (len<=40)

      // optimistic apply; exact count from atomic returns (single wave:
      // DS ops execute in issue order; no barriers needed)
      uint4 pre = *(const uint4*)&maskw[4 * lane];  // pre-batch snapshot
      int d = 0;
#pragma unroll
      for (int k = 0; k < 3; ++k) {
        int w = w0 + k;
        if (w <= w1) {
          unsigned bits = span_bits(start, end, w);
          unsigned old = atomicOr(&maskw[w], bits);
          d += __popc(bits & ~old);   // Σ over ops = |new union bits| exact
        }
      }
#pragma unroll
      for (int off = 1; off < 64; off <<= 1) d += __shfl_xor(d, off);
      const int newcur = cur + d;

      if (newcur < target) { cur = newcur; continue; }  // batch fully valid

      // ---- crossing batch: binary search for smallest n, count(n)>=target.
      // Invariant: count(lo) < target <= count(hi); count(0)=cur < target.
      int lo = 0, hi = 64;
      while (hi - lo > 1) {   // 6 probes
        const int mid = (lo + hi) >> 1;
        *(uint4*)&maskw[4 * lane] = pre;   // restore snapshot
        int dm = 0;
        if (lane < mid) {
#pragma unroll
          for (int k = 0; k < 3; ++k) {
            int w = w0 + k;
            if (w <= w1) {
              unsigned bits = span_bits(start, end, w);
              unsigned old = atomicOr(&maskw[w], bits);
              dm += __popc(bits & ~old);
            }
          }
        }
#pragma unroll
        for (int off = 1; off < 64; off <<= 1) dm += __shfl_xor(dm, off);
        if (cur + dm < target) lo = mid; else hi = mid;
      }
      // final state: prior mask ∪ spans_{0..hi-1}
      *(uint4*)&maskw[4 * lane] = pre;
      if (lane < hi) {
#pragma unroll
        for (int k = 0; k < 3; ++k) {
          int w = w0 + k;
          if (w <= w1) atomicOr(&maskw[w], span_bits(start, end, w));
        }
      }
      break;  // row done
    }
  }

  __syncthreads();  // waves 1-3 waited here during the walk

  // ---- epilogue: 4-wave int4 stores (tok[] loaded at kernel start) --------
#pragma unroll
  for (int k = 0; k < 8; ++k) {
    const int i = k * 256 + tid;
    unsigned nib = maskw[i >> 3] >> ((i & 7) * 4);
    int4 xm, mm;
    mm.x = (int)(nib & 1u);        xm.x = mm.x ? kMaskTok : tok[k].x;
    mm.y = (int)((nib >> 1) & 1u); xm.y = mm.y ? kMaskTok : tok[k].y;
    mm.z = (int)((nib >> 2) & 1u); xm.z = mm.z ? kMaskTok : tok[k].z;
    mm.w = (int)((nib >> 3) & 1u); xm.w = mm.w ? kMaskTok : tok[k].w;
    ((int4*)out)[base4 + i] = xm;
    ((int4*)out)[kB * (kS / 4) + base4 + i] = mm;
  }
}

extern "C" void kernel_launch(void* const* d_in, const int* in_sizes, int n_in,
                              void* d_out, int out_size, void* d_ws, size_t ws_size,
                              hipStream_t stream) {
  const int* x0 = (const int*)d_in[0];
  const float* mp = (const float*)d_in[1];
  int* out = (int*)d_out;
  hipLaunchKernelGGL(span_mask_kernel, dim3(kB), dim3(256), 0, stream,
                     x0, mp, out);
}